// Round 1
// 1041.404 us; speedup vs baseline: 1.1528x; 1.1528x over previous
//
#include <hip/hip_runtime.h>
#include <hip/hip_bf16.h>
#include <math.h>

#define BB 2
#define NN 768
#define DD 512
#define HH 16
#define DHH 32
#define PDD 128
#define ROWS (BB*NN)          // 1536

// workspace offsets (floats)
#define WC_OFF   0L           // 2048: pnw[e]*bias_w[e,h]
#define C12_OFF  2048L        // 16 c1 + 16 c2
#define X_OFF    4096L
#define QKV_OFF  (X_OFF    + 786432L)
#define GSIG_OFF (QKV_OFF  + 2359296L)
#define QN_OFF   (GSIG_OFF + 786432L)
#define KN_OFF   (QN_OFF   + 786432L)
#define OB_OFF   (KN_OFF   + 786432L)
#define BIAS_OFF (OB_OFF   + 786432L)   // layout: (b,h,i,j) = ((b*16+h)*768 + i)*768 + j
// end = 25169920 floats = 100.7 MB

__global__ __launch_bounds__(256) void k_prep(const float* __restrict__ pnw,
                                              const float* __restrict__ pnb,
                                              const float* __restrict__ bw,
                                              float* __restrict__ ws) {
    int t = threadIdx.x;
    for (int idx = t; idx < 2048; idx += 256)
        ws[WC_OFF + idx] = pnw[idx >> 4] * bw[idx];
    if (t < 16) {
        float a = 0.f, b = 0.f;
        for (int e = 0; e < 128; e++) { a += pnb[e] * bw[e*16 + t]; b += pnw[e] * bw[e*16 + t]; }
        ws[C12_OFF + t] = a;        // c1
        ws[C12_OFF + 16 + t] = b;   // c2
    }
}

// LayerNorm over 512 elems: one block per row
__global__ __launch_bounds__(256) void k_ln512(const float* __restrict__ in, long ld, long col0,
                                               const float* __restrict__ w, const float* __restrict__ bp,
                                               float* __restrict__ out) {
    int r = blockIdx.x, t = threadIdx.x;
    const float* src = in + (long)r * ld + col0;
    float v0 = src[t], v1 = src[t + 256];
    float s1 = v0 + v1, s2 = v0*v0 + v1*v1;
    __shared__ float red[16];
    #pragma unroll
    for (int off = 32; off > 0; off >>= 1) {
        s1 += __shfl_down(s1, off, 64);
        s2 += __shfl_down(s2, off, 64);
    }
    int wid = t >> 6, lane = t & 63;
    if (lane == 0) { red[wid] = s1; red[wid + 4] = s2; }
    __syncthreads();
    if (t == 0) {
        float a = red[0]+red[1]+red[2]+red[3];
        float c = red[4]+red[5]+red[6]+red[7];
        float mean = a / 512.f;
        float var  = c / 512.f - mean*mean;
        red[8] = mean; red[9] = rsqrtf(var + 1e-5f);
    }
    __syncthreads();
    float mean = red[8], rstd = red[9];
    out[(long)r*512 + t]       = (v0 - mean) * rstd * w[t]       + bp[t];
    out[(long)r*512 + t + 256] = (v1 - mean) * rstd * w[t + 256] + bp[t + 256];
}

// fused [qkv | g] GEMM; sigmoid folded into g
__global__ __launch_bounds__(256) void k_qkvg(const float* __restrict__ x,
                                              const float* __restrict__ qkv_w, const float* __restrict__ qkv_b,
                                              const float* __restrict__ g_w,  const float* __restrict__ g_b,
                                              float* __restrict__ qkv_o, float* __restrict__ gsig) {
    __shared__ float As[16][64];
    __shared__ float Bs[16][64];
    int bx = blockIdx.x, by = blockIdx.y, t = threadIdx.x;
    bool isg = (bx >= 24);
    const float* Wp = isg ? g_w : qkv_w;
    const float* bp = isg ? g_b : qkv_b;
    long ldw = isg ? 512 : 1536;
    int c0 = isg ? (bx - 24) * 64 : bx * 64;
    int tr = t >> 4, tc = t & 15;
    int am = t >> 2, ak = (t & 3) * 4;
    int bk = t >> 4, bc = (t & 15) * 4;
    const float* xrow = x + (long)(by*64 + am)*512 + ak;
    float acc[4][4] = {};
    for (int kt = 0; kt < 32; kt++) {
        float4 av = *(const float4*)(xrow + kt*16);
        float4 bv = *(const float4*)(Wp + (long)(kt*16 + bk)*ldw + c0 + bc);
        As[ak+0][am] = av.x; As[ak+1][am] = av.y; As[ak+2][am] = av.z; As[ak+3][am] = av.w;
        *(float4*)&Bs[bk][bc] = bv;
        __syncthreads();
        #pragma unroll
        for (int k = 0; k < 16; k++) {
            float4 a4 = *(const float4*)&As[k][tr*4];
            float4 b4 = *(const float4*)&Bs[k][tc*4];
            float ar[4] = {a4.x, a4.y, a4.z, a4.w};
            float br[4] = {b4.x, b4.y, b4.z, b4.w};
            #pragma unroll
            for (int r = 0; r < 4; r++)
                #pragma unroll
                for (int c = 0; c < 4; c++)
                    acc[r][c] = fmaf(ar[r], br[c], acc[r][c]);
        }
        __syncthreads();
    }
    #pragma unroll
    for (int r = 0; r < 4; r++) {
        int row = by*64 + tr*4 + r;
        #pragma unroll
        for (int c = 0; c < 4; c++) {
            int col = c0 + tc*4 + c;
            float val = acc[r][c] + bp[col];
            if (!isg) qkv_o[(long)row*1536 + col] = val;
            else      gsig[(long)row*512 + col] = 1.f / (1.f + __expf(-val));
        }
    }
}

// pair LN + bias einsum + mask; writes (b,h,i,j) layout.
// One thread owns TWO complete (b,i,j) rows (128 elems each), streamed from
// global in float4; 16 head accumulators + LN stats in registers. Only the
// 8 KB folded-weight table lives in LDS (uniform-address broadcast reads).
__global__ __launch_bounds__(256) void k_bias(const float* __restrict__ pair,
                                              const int* __restrict__ mask,
                                              const float* __restrict__ wsbase,
                                              float* __restrict__ bias_o) {
    __shared__ float wcs[2048];
    __shared__ float c12s[32];
    int t = threadIdx.x;
    for (int idx = t; idx < 2048; idx += 256) wcs[idx] = wsbase[WC_OFF + idx];
    if (t < 32) c12s[t] = wsbase[C12_OFF + t];
    __syncthreads();

    long g  = (long)blockIdx.x * 256 + t;   // row-pair index; grid covers exactly B*N*N/2
    long r0 = g * 2;                        // even row; r0,r0+1 share (b,i)
    const float4* p0 = (const float4*)pair + r0 * 32;

    float acc0[16] = {}, acc1[16] = {};
    float s0 = 0.f, q0 = 0.f, s1 = 0.f, q1 = 0.f;

    #pragma unroll 4
    for (int k = 0; k < 32; k++) {
        float4 a = p0[k];        // row r0, elems 4k..4k+3
        float4 b = p0[32 + k];   // row r0+1
        float ae[4] = {a.x, a.y, a.z, a.w};
        float be[4] = {b.x, b.y, b.z, b.w};
        const float* wr = &wcs[k * 64];
        #pragma unroll
        for (int e = 0; e < 4; e++) {
            float pa = ae[e], pb = be[e];
            s0 += pa; q0 = fmaf(pa, pa, q0);
            s1 += pb; q1 = fmaf(pb, pb, q1);
            #pragma unroll
            for (int h4 = 0; h4 < 4; h4++) {
                float4 w = *(const float4*)&wr[e * 16 + h4 * 4];
                acc0[h4*4+0] = fmaf(pa, w.x, acc0[h4*4+0]);
                acc0[h4*4+1] = fmaf(pa, w.y, acc0[h4*4+1]);
                acc0[h4*4+2] = fmaf(pa, w.z, acc0[h4*4+2]);
                acc0[h4*4+3] = fmaf(pa, w.w, acc0[h4*4+3]);
                acc1[h4*4+0] = fmaf(pb, w.x, acc1[h4*4+0]);
                acc1[h4*4+1] = fmaf(pb, w.y, acc1[h4*4+1]);
                acc1[h4*4+2] = fmaf(pb, w.z, acc1[h4*4+2]);
                acc1[h4*4+3] = fmaf(pb, w.w, acc1[h4*4+3]);
            }
        }
    }

    float mean0 = s0 * (1.f/128.f), mean1 = s1 * (1.f/128.f);
    float var0 = q0 * (1.f/128.f) - mean0*mean0;
    float var1 = q1 * (1.f/128.f) - mean1*mean1;
    float rs0 = rsqrtf(var0 + 1e-5f), rs1 = rsqrtf(var1 + 1e-5f);
    float rm0 = rs0 * mean0, rm1 = rs1 * mean1;

    int2 mk = *(const int2*)&mask[r0];      // mask is flat over (b,i,j)

    int  j0 = (int)(r0 % 768);              // even, so j0+1 stays in the same (b,i)
    long ri = r0 / 768;                     // = b*768 + i
    long b  = ri / 768;
    long i  = ri - b * 768;
    long obase = ((b * 16) * 768 + i) * 768 + j0;

    #pragma unroll
    for (int h = 0; h < 16; h++) {
        float c1h = c12s[h], c2h = c12s[16 + h];
        float base = fmaf(-rm0, c2h, c1h);
        float v0 = mk.x ? fmaf(rs0, acc0[h], base) : -10000.f;
        float base1 = fmaf(-rm1, c2h, c1h);
        float v1 = mk.y ? fmaf(rs1, acc1[h], base1) : -10000.f;
        *(float2*)&bias_o[obase + (long)h * (768L*768L)] = make_float2(v0, v1);
    }
}

// flash attention: block = (i-tile of 16 rows, b*16+h); 128 threads = 8 row-pairs x 16 j-slots
__global__ __launch_bounds__(128) void k_attn(const float* __restrict__ qn,
                                              const float* __restrict__ kn,
                                              const float* __restrict__ qkv,
                                              const float* __restrict__ gsig,
                                              const float* __restrict__ bias,
                                              float* __restrict__ obuf) {
    __shared__ float Ks[64][36];
    __shared__ float Vs[64][36];
    int it = blockIdx.x, bh = blockIdx.y;
    int b = bh >> 4, h = bh & 15;
    int t = threadIdx.x;
    int rg = t >> 4, s = t & 15;
    int i0 = it*16 + rg*2;                 // first of the 2 rows this thread owns
    const float* qp = qn + ((long)(b*NN) + i0)*512 + h*32;
    float4 q0[8], q1[8];
    #pragma unroll
    for (int c = 0; c < 8; c++) {
        q0[c] = ((const float4*)qp)[c];
        q1[c] = ((const float4*)(qp + 512))[c];
    }
    float m0 = -1e30f, m1 = -1e30f, l0 = 0.f, l1 = 0.f;
    float4 o0[8], o1[8];
    #pragma unroll
    for (int c = 0; c < 8; c++) { o0[c] = make_float4(0,0,0,0); o1[c] = make_float4(0,0,0,0); }
    const long bias0 = ((long)bh*NN + i0)*NN;
    const float scale = 0.17677669529663687f;

    for (int jt = 0; jt < 12; jt++) {
        int j0 = jt*64;
        __syncthreads();
        #pragma unroll
        for (int k = 0; k < 4; k++) {
            int f = t + k*128;
            int row = f >> 3, ch = (f & 7)*4;
            *(float4*)&Ks[row][ch] = *(const float4*)(kn  + ((long)(b*NN) + j0 + row)*512  + h*32 + ch);
            *(float4*)&Vs[row][ch] = *(const float4*)(qkv + ((long)(b*NN) + j0 + row)*1536 + 1024 + h*32 + ch);
        }
        __syncthreads();
        #pragma unroll
        for (int st = 0; st < 4; st++) {
            int j = s + st*16;
            float d0 = 0.f, d1 = 0.f;
            #pragma unroll
            for (int c = 0; c < 8; c++) {
                float4 kv = *(const float4*)&Ks[j][c*4];
                d0 = fmaf(kv.x, q0[c].x, d0); d0 = fmaf(kv.y, q0[c].y, d0);
                d0 = fmaf(kv.z, q0[c].z, d0); d0 = fmaf(kv.w, q0[c].w, d0);
                d1 = fmaf(kv.x, q1[c].x, d1); d1 = fmaf(kv.y, q1[c].y, d1);
                d1 = fmaf(kv.z, q1[c].z, d1); d1 = fmaf(kv.w, q1[c].w, d1);
            }
            float b0v = bias[bias0 + j0 + j];
            float b1v = bias[bias0 + NN + j0 + j];
            float s0 = fmaf(d0, scale, b0v);
            float s1 = fmaf(d1, scale, b1v);
            float mn0 = fmaxf(m0, s0), mn1 = fmaxf(m1, s1);
            float p0 = __expf(s0 - mn0), p1 = __expf(s1 - mn1);
            if (__any((s0 > m0) || (s1 > m1))) {
                float c0 = __expf(m0 - mn0), c1 = __expf(m1 - mn1);
                l0 = l0*c0 + p0; l1 = l1*c1 + p1;
                m0 = mn0; m1 = mn1;
                #pragma unroll
                for (int c = 0; c < 8; c++) {
                    float4 vv = *(const float4*)&Vs[j][c*4];
                    o0[c].x = fmaf(o0[c].x, c0, p0*vv.x); o0[c].y = fmaf(o0[c].y, c0, p0*vv.y);
                    o0[c].z = fmaf(o0[c].z, c0, p0*vv.z); o0[c].w = fmaf(o0[c].w, c0, p0*vv.w);
                    o1[c].x = fmaf(o1[c].x, c1, p1*vv.x); o1[c].y = fmaf(o1[c].y, c1, p1*vv.y);
                    o1[c].z = fmaf(o1[c].z, c1, p1*vv.z); o1[c].w = fmaf(o1[c].w, c1, p1*vv.w);
                }
            } else {
                l0 += p0; l1 += p1;
                #pragma unroll
                for (int c = 0; c < 8; c++) {
                    float4 vv = *(const float4*)&Vs[j][c*4];
                    o0[c].x = fmaf(p0, vv.x, o0[c].x); o0[c].y = fmaf(p0, vv.y, o0[c].y);
                    o0[c].z = fmaf(p0, vv.z, o0[c].z); o0[c].w = fmaf(p0, vv.w, o0[c].w);
                    o1[c].x = fmaf(p1, vv.x, o1[c].x); o1[c].y = fmaf(p1, vv.y, o1[c].y);
                    o1[c].z = fmaf(p1, vv.z, o1[c].z); o1[c].w = fmaf(p1, vv.w, o1[c].w);
                }
            }
        }
    }
    // merge the 16 slot-partials (lanes within 16-group, same wave)
    #pragma unroll
    for (int mk = 1; mk < 16; mk <<= 1) {
        float mo0 = __shfl_xor(m0, mk, 64), mo1 = __shfl_xor(m1, mk, 64);
        float lo0 = __shfl_xor(l0, mk, 64), lo1 = __shfl_xor(l1, mk, 64);
        float nm0 = fmaxf(m0, mo0), nm1 = fmaxf(m1, mo1);
        float a0 = __expf(m0 - nm0), b0 = __expf(mo0 - nm0);
        float a1 = __expf(m1 - nm1), b1 = __expf(mo1 - nm1);
        l0 = l0*a0 + lo0*b0; l1 = l1*a1 + lo1*b1;
        m0 = nm0; m1 = nm1;
        #pragma unroll
        for (int c = 0; c < 8; c++) {
            float4 t0, t1;
            t0.x = __shfl_xor(o0[c].x, mk, 64); t0.y = __shfl_xor(o0[c].y, mk, 64);
            t0.z = __shfl_xor(o0[c].z, mk, 64); t0.w = __shfl_xor(o0[c].w, mk, 64);
            t1.x = __shfl_xor(o1[c].x, mk, 64); t1.y = __shfl_xor(o1[c].y, mk, 64);
            t1.z = __shfl_xor(o1[c].z, mk, 64); t1.w = __shfl_xor(o1[c].w, mk, 64);
            o0[c].x = fmaf(t0.x, b0, o0[c].x*a0); o0[c].y = fmaf(t0.y, b0, o0[c].y*a0);
            o0[c].z = fmaf(t0.z, b0, o0[c].z*a0); o0[c].w = fmaf(t0.w, b0, o0[c].w*a0);
            o1[c].x = fmaf(t1.x, b1, o1[c].x*a1); o1[c].y = fmaf(t1.y, b1, o1[c].y*a1);
            o1[c].z = fmaf(t1.z, b1, o1[c].z*a1); o1[c].w = fmaf(t1.w, b1, o1[c].w*a1);
        }
    }
    // epilogue: lane s -> row (s>>3), float4 chunk (s&7); select via cndmask chain
    int rsel = s >> 3, cs = s & 7;
    float4 a0 = o0[0], a1 = o1[0];
    #pragma unroll
    for (int k = 1; k < 8; k++) {
        bool c = (cs == k);
        a0.x = c ? o0[k].x : a0.x; a0.y = c ? o0[k].y : a0.y;
        a0.z = c ? o0[k].z : a0.z; a0.w = c ? o0[k].w : a0.w;
        a1.x = c ? o1[k].x : a1.x; a1.y = c ? o1[k].y : a1.y;
        a1.z = c ? o1[k].z : a1.z; a1.w = c ? o1[k].w : a1.w;
    }
    float4 ov;
    ov.x = rsel ? a1.x : a0.x; ov.y = rsel ? a1.y : a0.y;
    ov.z = rsel ? a1.z : a0.z; ov.w = rsel ? a1.w : a0.w;
    float inv = 1.f / (rsel ? l1 : l0);
    long base = ((long)(b*NN) + i0 + rsel)*512 + h*32 + cs*4;
    float4 g = *(const float4*)(gsig + base);
    float4 r;
    r.x = g.x * ov.x * inv; r.y = g.y * ov.y * inv;
    r.z = g.z * ov.z * inv; r.w = g.w * ov.w * inv;
    *(float4*)(obuf + base) = r;
}

// out projection: obuf(1536x512) @ out_w(512x512) + out_b
__global__ __launch_bounds__(256) void k_out(const float* __restrict__ ob,
                                             const float* __restrict__ w,
                                             const float* __restrict__ bp,
                                             float* __restrict__ out) {
    __shared__ float As[16][64];
    __shared__ float Bs[16][64];
    int bx = blockIdx.x, by = blockIdx.y, t = threadIdx.x;
    int c0 = bx * 64;
    int tr = t >> 4, tc = t & 15;
    int am = t >> 2, ak = (t & 3) * 4;
    int bk = t >> 4, bc = (t & 15) * 4;
    const float* xrow = ob + (long)(by*64 + am)*512 + ak;
    float acc[4][4] = {};
    for (int kt = 0; kt < 32; kt++) {
        float4 av = *(const float4*)(xrow + kt*16);
        float4 bv = *(const float4*)(w + (long)(kt*16 + bk)*512 + c0 + bc);
        As[ak+0][am] = av.x; As[ak+1][am] = av.y; As[ak+2][am] = av.z; As[ak+3][am] = av.w;
        *(float4*)&Bs[bk][bc] = bv;
        __syncthreads();
        #pragma unroll
        for (int k = 0; k < 16; k++) {
            float4 a4 = *(const float4*)&As[k][tr*4];
            float4 b4 = *(const float4*)&Bs[k][tc*4];
            float ar[4] = {a4.x, a4.y, a4.z, a4.w};
            float br[4] = {b4.x, b4.y, b4.z, b4.w};
            #pragma unroll
            for (int r = 0; r < 4; r++)
                #pragma unroll
                for (int c = 0; c < 4; c++)
                    acc[r][c] = fmaf(ar[r], br[c], acc[r][c]);
        }
        __syncthreads();
    }
    #pragma unroll
    for (int r = 0; r < 4; r++) {
        int row = by*64 + tr*4 + r;
        #pragma unroll
        for (int c = 0; c < 4; c++) {
            int col = c0 + tc*4 + c;
            out[(long)row*512 + col] = acc[r][c] + bp[col];
        }
    }
}

extern "C" void kernel_launch(void* const* d_in, const int* in_sizes, int n_in,
                              void* d_out, int out_size, void* d_ws, size_t ws_size,
                              hipStream_t stream) {
    const float* node_feats = (const float*)d_in[0];
    const float* pair_feats = (const float*)d_in[1];
    const int*   mask       = (const int*)d_in[2];
    const float* node_w     = (const float*)d_in[3];
    const float* node_b     = (const float*)d_in[4];
    const float* qkv_w      = (const float*)d_in[5];
    const float* qkv_b      = (const float*)d_in[6];
    const float* g_w        = (const float*)d_in[7];
    const float* g_b        = (const float*)d_in[8];
    const float* qln_w      = (const float*)d_in[9];
    const float* qln_b      = (const float*)d_in[10];
    const float* kln_w      = (const float*)d_in[11];
    const float* kln_b      = (const float*)d_in[12];
    const float* pnw        = (const float*)d_in[13];
    const float* pnb        = (const float*)d_in[14];
    const float* bias_w     = (const float*)d_in[15];
    const float* out_w      = (const float*)d_in[16];
    const float* out_b      = (const float*)d_in[17];
    float* out = (float*)d_out;
    float* ws  = (float*)d_ws;

    float* x_buf    = ws + X_OFF;
    float* qkv_buf  = ws + QKV_OFF;
    float* gsig_buf = ws + GSIG_OFF;
    float* qn_buf   = ws + QN_OFF;
    float* kn_buf   = ws + KN_OFF;
    float* ob_buf   = ws + OB_OFF;
    float* bias_buf = ws + BIAS_OFF;

    k_prep<<<1, 256, 0, stream>>>(pnw, pnb, bias_w, ws);
    k_ln512<<<ROWS, 256, 0, stream>>>(node_feats, 512, 0, node_w, node_b, x_buf);
    k_qkvg<<<dim3(32, 24), 256, 0, stream>>>(x_buf, qkv_w, qkv_b, g_w, g_b, qkv_buf, gsig_buf);
    k_ln512<<<ROWS, 256, 0, stream>>>(qkv_buf, 1536, 0,   qln_w, qln_b, qn_buf);
    k_ln512<<<ROWS, 256, 0, stream>>>(qkv_buf, 1536, 512, kln_w, kln_b, kn_buf);
    // B*N*N/2 row-pairs / 256 threads = 2304 blocks (exact)
    k_bias<<<2304, 256, 0, stream>>>(pair_feats, mask, ws, bias_buf);
    k_attn<<<dim3(48, 32), 128, 0, stream>>>(qn_buf, kn_buf, qkv_buf, gsig_buf, bias_buf, ob_buf);
    k_out<<<dim3(8, 24), 256, 0, stream>>>(ob_buf, out_w, out_b, out);
}

// Round 2
// 1028.241 us; speedup vs baseline: 1.1675x; 1.0128x over previous
//
#include <hip/hip_runtime.h>
#include <hip/hip_bf16.h>
#include <math.h>

#define BB 2
#define NN 768
#define DD 512
#define HH 16
#define DHH 32
#define PDD 128
#define ROWS (BB*NN)          // 1536

// workspace offsets (floats)
#define WC_OFF   0L           // 2048: pnw[e]*bias_w[e,h]
#define C12_OFF  2048L        // 16 c1 + 16 c2
#define X_OFF    4096L
#define QKV_OFF  (X_OFF    + 786432L)
#define GSIG_OFF (QKV_OFF  + 2359296L)
#define QN_OFF   (GSIG_OFF + 786432L)
#define KN_OFF   (QN_OFF   + 786432L)
#define OB_OFF   (KN_OFF   + 786432L)
#define BIAS_OFF (OB_OFF   + 786432L)   // layout: (b,h,i,j) = ((b*16+h)*768 + i)*768 + j
// end = 25169920 floats = 100.7 MB

__global__ __launch_bounds__(256) void k_prep(const float* __restrict__ pnw,
                                              const float* __restrict__ pnb,
                                              const float* __restrict__ bw,
                                              float* __restrict__ ws) {
    int t = threadIdx.x;
    for (int idx = t; idx < 2048; idx += 256)
        ws[WC_OFF + idx] = pnw[idx >> 4] * bw[idx];
    if (t < 16) {
        float a = 0.f, b = 0.f;
        for (int e = 0; e < 128; e++) { a += pnb[e] * bw[e*16 + t]; b += pnw[e] * bw[e*16 + t]; }
        ws[C12_OFF + t] = a;        // c1
        ws[C12_OFF + 16 + t] = b;   // c2
    }
}

// LayerNorm over 512 elems: one block per row
__global__ __launch_bounds__(256) void k_ln512(const float* __restrict__ in, long ld, long col0,
                                               const float* __restrict__ w, const float* __restrict__ bp,
                                               float* __restrict__ out) {
    int r = blockIdx.x, t = threadIdx.x;
    const float* src = in + (long)r * ld + col0;
    float v0 = src[t], v1 = src[t + 256];
    float s1 = v0 + v1, s2 = v0*v0 + v1*v1;
    __shared__ float red[16];
    #pragma unroll
    for (int off = 32; off > 0; off >>= 1) {
        s1 += __shfl_down(s1, off, 64);
        s2 += __shfl_down(s2, off, 64);
    }
    int wid = t >> 6, lane = t & 63;
    if (lane == 0) { red[wid] = s1; red[wid + 4] = s2; }
    __syncthreads();
    if (t == 0) {
        float a = red[0]+red[1]+red[2]+red[3];
        float c = red[4]+red[5]+red[6]+red[7];
        float mean = a / 512.f;
        float var  = c / 512.f - mean*mean;
        red[8] = mean; red[9] = rsqrtf(var + 1e-5f);
    }
    __syncthreads();
    float mean = red[8], rstd = red[9];
    out[(long)r*512 + t]       = (v0 - mean) * rstd * w[t]       + bp[t];
    out[(long)r*512 + t + 256] = (v1 - mean) * rstd * w[t + 256] + bp[t + 256];
}

// fused [qkv | g] GEMM; sigmoid folded into g
__global__ __launch_bounds__(256) void k_qkvg(const float* __restrict__ x,
                                              const float* __restrict__ qkv_w, const float* __restrict__ qkv_b,
                                              const float* __restrict__ g_w,  const float* __restrict__ g_b,
                                              float* __restrict__ qkv_o, float* __restrict__ gsig) {
    __shared__ float As[16][64];
    __shared__ float Bs[16][64];
    int bx = blockIdx.x, by = blockIdx.y, t = threadIdx.x;
    bool isg = (bx >= 24);
    const float* Wp = isg ? g_w : qkv_w;
    const float* bp = isg ? g_b : qkv_b;
    long ldw = isg ? 512 : 1536;
    int c0 = isg ? (bx - 24) * 64 : bx * 64;
    int tr = t >> 4, tc = t & 15;
    int am = t >> 2, ak = (t & 3) * 4;
    int bk = t >> 4, bc = (t & 15) * 4;
    const float* xrow = x + (long)(by*64 + am)*512 + ak;
    float acc[4][4] = {};
    for (int kt = 0; kt < 32; kt++) {
        float4 av = *(const float4*)(xrow + kt*16);
        float4 bv = *(const float4*)(Wp + (long)(kt*16 + bk)*ldw + c0 + bc);
        As[ak+0][am] = av.x; As[ak+1][am] = av.y; As[ak+2][am] = av.z; As[ak+3][am] = av.w;
        *(float4*)&Bs[bk][bc] = bv;
        __syncthreads();
        #pragma unroll
        for (int k = 0; k < 16; k++) {
            float4 a4 = *(const float4*)&As[k][tr*4];
            float4 b4 = *(const float4*)&Bs[k][tc*4];
            float ar[4] = {a4.x, a4.y, a4.z, a4.w};
            float br[4] = {b4.x, b4.y, b4.z, b4.w};
            #pragma unroll
            for (int r = 0; r < 4; r++)
                #pragma unroll
                for (int c = 0; c < 4; c++)
                    acc[r][c] = fmaf(ar[r], br[c], acc[r][c]);
        }
        __syncthreads();
    }
    #pragma unroll
    for (int r = 0; r < 4; r++) {
        int row = by*64 + tr*4 + r;
        #pragma unroll
        for (int c = 0; c < 4; c++) {
            int col = c0 + tc*4 + c;
            float val = acc[r][c] + bp[col];
            if (!isg) qkv_o[(long)row*1536 + col] = val;
            else      gsig[(long)row*512 + col] = 1.f / (1.f + __expf(-val));
        }
    }
}

// pair LN + bias einsum + mask; writes (b,h,i,j) layout.
// Block owns 256 rows; 4 chunks of 32 floats (one full 128B line per row per
// chunk). Coalesced global->reg->LDS staging (pad-33 => all LDS ops 2-way =
// free); weights read with wave-uniform addresses directly from the workspace
// (-> s_load, SMEM pipe, zero VALU/LDS cost). Issue chunk c+1 loads before
// computing chunk c to hide HBM latency.
__global__ __launch_bounds__(256) void k_bias(const float* __restrict__ pair,
                                              const int* __restrict__ mask,
                                              const float* __restrict__ wsbase,
                                              float* __restrict__ bias_o) {
    __shared__ float bufs[256 * 33];
    const float* wc  = wsbase + WC_OFF;    // 2048 floats, uniform reads
    const float* c12 = wsbase + C12_OFF;   // 32 floats, uniform reads
    int t = threadIdx.x;
    long row0 = (long)blockIdx.x * 256;
    const float4* pf = (const float4*)pair + row0 * 32;

    float acc[16] = {};
    float s0 = 0.f, q0 = 0.f;

    float4 stg[8];
    #pragma unroll
    for (int it = 0; it < 8; it++) {
        int f = t + it * 256;
        int row = f >> 3, q = f & 7;
        stg[it] = pf[(long)row * 32 + q];
    }

    for (int c = 0; c < 4; c++) {
        __syncthreads();                    // buf free (prev chunk consumed)
        #pragma unroll
        for (int it = 0; it < 8; it++) {
            int f = t + it * 256;
            int row = f >> 3, q = f & 7;
            float* d = &bufs[row * 33 + q * 4];
            d[0] = stg[it].x; d[1] = stg[it].y; d[2] = stg[it].z; d[3] = stg[it].w;
        }
        __syncthreads();                    // buf ready
        if (c < 3) {                        // issue next chunk's loads early
            #pragma unroll
            for (int it = 0; it < 8; it++) {
                int f = t + it * 256;
                int row = f >> 3, q = f & 7;
                stg[it] = pf[(long)row * 32 + (c + 1) * 8 + q];
            }
        }
        const float* wck = wc + c * 512;    // 32 elems x 16 heads
        const float* dr  = &bufs[t * 33];
        #pragma unroll
        for (int k = 0; k < 32; k++) {
            float d = dr[k];
            s0 += d; q0 = fmaf(d, d, q0);
            #pragma unroll
            for (int h4 = 0; h4 < 4; h4++) {
                float4 w = *(const float4*)(wck + k * 16 + h4 * 4);  // uniform -> s_load
                acc[h4*4+0] = fmaf(d, w.x, acc[h4*4+0]);
                acc[h4*4+1] = fmaf(d, w.y, acc[h4*4+1]);
                acc[h4*4+2] = fmaf(d, w.z, acc[h4*4+2]);
                acc[h4*4+3] = fmaf(d, w.w, acc[h4*4+3]);
            }
        }
    }

    float mean = s0 * (1.f/128.f);
    float var  = q0 * (1.f/128.f) - mean * mean;
    float rs   = rsqrtf(var + 1e-5f);
    float rm   = rs * mean;

    long r  = row0 + t;
    int  mk = mask[r];
    long j  = r % 768;
    long ri = r / 768;                      // b*768 + i
    long b  = ri / 768;
    long i  = ri - b * 768;
    long ob = ((b * 16) * 768 + i) * 768 + j;

    #pragma unroll
    for (int h = 0; h < 16; h++) {
        float c1h = c12[h], c2h = c12[16 + h];     // uniform -> s_load
        float v = mk ? fmaf(rs, acc[h], fmaf(-rm, c2h, c1h)) : -10000.f;
        bias_o[ob + (long)h * (768L * 768L)] = v;
    }
}

// flash attention: block = (i-tile of 16 rows, b*16+h); 128 threads = 8 row-pairs x 16 j-slots
__global__ __launch_bounds__(128) void k_attn(const float* __restrict__ qn,
                                              const float* __restrict__ kn,
                                              const float* __restrict__ qkv,
                                              const float* __restrict__ gsig,
                                              const float* __restrict__ bias,
                                              float* __restrict__ obuf) {
    __shared__ float Ks[64][36];
    __shared__ float Vs[64][36];
    int it = blockIdx.x, bh = blockIdx.y;
    int b = bh >> 4, h = bh & 15;
    int t = threadIdx.x;
    int rg = t >> 4, s = t & 15;
    int i0 = it*16 + rg*2;                 // first of the 2 rows this thread owns
    const float* qp = qn + ((long)(b*NN) + i0)*512 + h*32;
    float4 q0[8], q1[8];
    #pragma unroll
    for (int c = 0; c < 8; c++) {
        q0[c] = ((const float4*)qp)[c];
        q1[c] = ((const float4*)(qp + 512))[c];
    }
    float m0 = -1e30f, m1 = -1e30f, l0 = 0.f, l1 = 0.f;
    float4 o0[8], o1[8];
    #pragma unroll
    for (int c = 0; c < 8; c++) { o0[c] = make_float4(0,0,0,0); o1[c] = make_float4(0,0,0,0); }
    const long bias0 = ((long)bh*NN + i0)*NN;
    const float scale = 0.17677669529663687f;

    for (int jt = 0; jt < 12; jt++) {
        int j0 = jt*64;
        __syncthreads();
        #pragma unroll
        for (int k = 0; k < 4; k++) {
            int f = t + k*128;
            int row = f >> 3, ch = (f & 7)*4;
            *(float4*)&Ks[row][ch] = *(const float4*)(kn  + ((long)(b*NN) + j0 + row)*512  + h*32 + ch);
            *(float4*)&Vs[row][ch] = *(const float4*)(qkv + ((long)(b*NN) + j0 + row)*1536 + 1024 + h*32 + ch);
        }
        __syncthreads();
        #pragma unroll
        for (int st = 0; st < 4; st++) {
            int j = s + st*16;
            float d0 = 0.f, d1 = 0.f;
            #pragma unroll
            for (int c = 0; c < 8; c++) {
                float4 kv = *(const float4*)&Ks[j][c*4];
                d0 = fmaf(kv.x, q0[c].x, d0); d0 = fmaf(kv.y, q0[c].y, d0);
                d0 = fmaf(kv.z, q0[c].z, d0); d0 = fmaf(kv.w, q0[c].w, d0);
                d1 = fmaf(kv.x, q1[c].x, d1); d1 = fmaf(kv.y, q1[c].y, d1);
                d1 = fmaf(kv.z, q1[c].z, d1); d1 = fmaf(kv.w, q1[c].w, d1);
            }
            float b0v = bias[bias0 + j0 + j];
            float b1v = bias[bias0 + NN + j0 + j];
            float s0 = fmaf(d0, scale, b0v);
            float s1 = fmaf(d1, scale, b1v);
            float mn0 = fmaxf(m0, s0), mn1 = fmaxf(m1, s1);
            float p0 = __expf(s0 - mn0), p1 = __expf(s1 - mn1);
            if (__any((s0 > m0) || (s1 > m1))) {
                float c0 = __expf(m0 - mn0), c1 = __expf(m1 - mn1);
                l0 = l0*c0 + p0; l1 = l1*c1 + p1;
                m0 = mn0; m1 = mn1;
                #pragma unroll
                for (int c = 0; c < 8; c++) {
                    float4 vv = *(const float4*)&Vs[j][c*4];
                    o0[c].x = fmaf(o0[c].x, c0, p0*vv.x); o0[c].y = fmaf(o0[c].y, c0, p0*vv.y);
                    o0[c].z = fmaf(o0[c].z, c0, p0*vv.z); o0[c].w = fmaf(o0[c].w, c0, p0*vv.w);
                    o1[c].x = fmaf(o1[c].x, c1, p1*vv.x); o1[c].y = fmaf(o1[c].y, c1, p1*vv.y);
                    o1[c].z = fmaf(o1[c].z, c1, p1*vv.z); o1[c].w = fmaf(o1[c].w, c1, p1*vv.w);
                }
            } else {
                l0 += p0; l1 += p1;
                #pragma unroll
                for (int c = 0; c < 8; c++) {
                    float4 vv = *(const float4*)&Vs[j][c*4];
                    o0[c].x = fmaf(p0, vv.x, o0[c].x); o0[c].y = fmaf(p0, vv.y, o0[c].y);
                    o0[c].z = fmaf(p0, vv.z, o0[c].z); o0[c].w = fmaf(p0, vv.w, o0[c].w);
                    o1[c].x = fmaf(p1, vv.x, o1[c].x); o1[c].y = fmaf(p1, vv.y, o1[c].y);
                    o1[c].z = fmaf(p1, vv.z, o1[c].z); o1[c].w = fmaf(p1, vv.w, o1[c].w);
                }
            }
        }
    }
    // merge the 16 slot-partials (lanes within 16-group, same wave)
    #pragma unroll
    for (int mk = 1; mk < 16; mk <<= 1) {
        float mo0 = __shfl_xor(m0, mk, 64), mo1 = __shfl_xor(m1, mk, 64);
        float lo0 = __shfl_xor(l0, mk, 64), lo1 = __shfl_xor(l1, mk, 64);
        float nm0 = fmaxf(m0, mo0), nm1 = fmaxf(m1, mo1);
        float a0 = __expf(m0 - nm0), b0 = __expf(mo0 - nm0);
        float a1 = __expf(m1 - nm1), b1 = __expf(mo1 - nm1);
        l0 = l0*a0 + lo0*b0; l1 = l1*a1 + lo1*b1;
        m0 = nm0; m1 = nm1;
        #pragma unroll
        for (int c = 0; c < 8; c++) {
            float4 t0, t1;
            t0.x = __shfl_xor(o0[c].x, mk, 64); t0.y = __shfl_xor(o0[c].y, mk, 64);
            t0.z = __shfl_xor(o0[c].z, mk, 64); t0.w = __shfl_xor(o0[c].w, mk, 64);
            t1.x = __shfl_xor(o1[c].x, mk, 64); t1.y = __shfl_xor(o1[c].y, mk, 64);
            t1.z = __shfl_xor(o1[c].z, mk, 64); t1.w = __shfl_xor(o1[c].w, mk, 64);
            o0[c].x = fmaf(t0.x, b0, o0[c].x*a0); o0[c].y = fmaf(t0.y, b0, o0[c].y*a0);
            o0[c].z = fmaf(t0.z, b0, o0[c].z*a0); o0[c].w = fmaf(t0.w, b0, o0[c].w*a0);
            o1[c].x = fmaf(t1.x, b1, o1[c].x*a1); o1[c].y = fmaf(t1.y, b1, o1[c].y*a1);
            o1[c].z = fmaf(t1.z, b1, o1[c].z*a1); o1[c].w = fmaf(t1.w, b1, o1[c].w*a1);
        }
    }
    // epilogue: lane s -> row (s>>3), float4 chunk (s&7); select via cndmask chain
    int rsel = s >> 3, cs = s & 7;
    float4 a0 = o0[0], a1 = o1[0];
    #pragma unroll
    for (int k = 1; k < 8; k++) {
        bool c = (cs == k);
        a0.x = c ? o0[k].x : a0.x; a0.y = c ? o0[k].y : a0.y;
        a0.z = c ? o0[k].z : a0.z; a0.w = c ? o0[k].w : a0.w;
        a1.x = c ? o1[k].x : a1.x; a1.y = c ? o1[k].y : a1.y;
        a1.z = c ? o1[k].z : a1.z; a1.w = c ? o1[k].w : a1.w;
    }
    float4 ov;
    ov.x = rsel ? a1.x : a0.x; ov.y = rsel ? a1.y : a0.y;
    ov.z = rsel ? a1.z : a0.z; ov.w = rsel ? a1.w : a0.w;
    float inv = 1.f / (rsel ? l1 : l0);
    long base = ((long)(b*NN) + i0 + rsel)*512 + h*32 + cs*4;
    float4 g = *(const float4*)(gsig + base);
    float4 r;
    r.x = g.x * ov.x * inv; r.y = g.y * ov.y * inv;
    r.z = g.z * ov.z * inv; r.w = g.w * ov.w * inv;
    *(float4*)(obuf + base) = r;
}

// out projection: obuf(1536x512) @ out_w(512x512) + out_b
__global__ __launch_bounds__(256) void k_out(const float* __restrict__ ob,
                                             const float* __restrict__ w,
                                             const float* __restrict__ bp,
                                             float* __restrict__ out) {
    __shared__ float As[16][64];
    __shared__ float Bs[16][64];
    int bx = blockIdx.x, by = blockIdx.y, t = threadIdx.x;
    int c0 = bx * 64;
    int tr = t >> 4, tc = t & 15;
    int am = t >> 2, ak = (t & 3) * 4;
    int bk = t >> 4, bc = (t & 15) * 4;
    const float* xrow = ob + (long)(by*64 + am)*512 + ak;
    float acc[4][4] = {};
    for (int kt = 0; kt < 32; kt++) {
        float4 av = *(const float4*)(xrow + kt*16);
        float4 bv = *(const float4*)(w + (long)(kt*16 + bk)*512 + c0 + bc);
        As[ak+0][am] = av.x; As[ak+1][am] = av.y; As[ak+2][am] = av.z; As[ak+3][am] = av.w;
        *(float4*)&Bs[bk][bc] = bv;
        __syncthreads();
        #pragma unroll
        for (int k = 0; k < 16; k++) {
            float4 a4 = *(const float4*)&As[k][tr*4];
            float4 b4 = *(const float4*)&Bs[k][tc*4];
            float ar[4] = {a4.x, a4.y, a4.z, a4.w};
            float br[4] = {b4.x, b4.y, b4.z, b4.w};
            #pragma unroll
            for (int r = 0; r < 4; r++)
                #pragma unroll
                for (int c = 0; c < 4; c++)
                    acc[r][c] = fmaf(ar[r], br[c], acc[r][c]);
        }
        __syncthreads();
    }
    #pragma unroll
    for (int r = 0; r < 4; r++) {
        int row = by*64 + tr*4 + r;
        #pragma unroll
        for (int c = 0; c < 4; c++) {
            int col = c0 + tc*4 + c;
            out[(long)row*512 + col] = acc[r][c] + bp[col];
        }
    }
}

extern "C" void kernel_launch(void* const* d_in, const int* in_sizes, int n_in,
                              void* d_out, int out_size, void* d_ws, size_t ws_size,
                              hipStream_t stream) {
    const float* node_feats = (const float*)d_in[0];
    const float* pair_feats = (const float*)d_in[1];
    const int*   mask       = (const int*)d_in[2];
    const float* node_w     = (const float*)d_in[3];
    const float* node_b     = (const float*)d_in[4];
    const float* qkv_w      = (const float*)d_in[5];
    const float* qkv_b      = (const float*)d_in[6];
    const float* g_w        = (const float*)d_in[7];
    const float* g_b        = (const float*)d_in[8];
    const float* qln_w      = (const float*)d_in[9];
    const float* qln_b      = (const float*)d_in[10];
    const float* kln_w      = (const float*)d_in[11];
    const float* kln_b      = (const float*)d_in[12];
    const float* pnw        = (const float*)d_in[13];
    const float* pnb        = (const float*)d_in[14];
    const float* bias_w     = (const float*)d_in[15];
    const float* out_w      = (const float*)d_in[16];
    const float* out_b      = (const float*)d_in[17];
    float* out = (float*)d_out;
    float* ws  = (float*)d_ws;

    float* x_buf    = ws + X_OFF;
    float* qkv_buf  = ws + QKV_OFF;
    float* gsig_buf = ws + GSIG_OFF;
    float* qn_buf   = ws + QN_OFF;
    float* kn_buf   = ws + KN_OFF;
    float* ob_buf   = ws + OB_OFF;
    float* bias_buf = ws + BIAS_OFF;

    k_prep<<<1, 256, 0, stream>>>(pnw, pnb, bias_w, ws);
    k_ln512<<<ROWS, 256, 0, stream>>>(node_feats, 512, 0, node_w, node_b, x_buf);
    k_qkvg<<<dim3(32, 24), 256, 0, stream>>>(x_buf, qkv_w, qkv_b, g_w, g_b, qkv_buf, gsig_buf);
    k_ln512<<<ROWS, 256, 0, stream>>>(qkv_buf, 1536, 0,   qln_w, qln_b, qn_buf);
    k_ln512<<<ROWS, 256, 0, stream>>>(qkv_buf, 1536, 512, kln_w, kln_b, kn_buf);
    // B*N*N rows / 256 rows-per-block = 4608 blocks (exact)
    k_bias<<<4608, 256, 0, stream>>>(pair_feats, mask, ws, bias_buf);
    k_attn<<<dim3(48, 32), 128, 0, stream>>>(qn_buf, kn_buf, qkv_buf, gsig_buf, bias_buf, ob_buf);
    k_out<<<dim3(8, 24), 256, 0, stream>>>(ob_buf, out_w, out_b, out);
}